// Round 13
// baseline (638.948 us; speedup 1.0000x reference)
//
#include <hip/hip_runtime.h>
#include <hip/hip_bf16.h>
#include <math.h>

using short8 = __attribute__((ext_vector_type(8))) short;
using f32x4  = __attribute__((ext_vector_type(4))) float;

static __device__ __forceinline__ f32x4 mfma16(short8 a, short8 b, f32x4 c){
    return __builtin_amdgcn_mfma_f32_16x16x32_bf16(a, b, c, 0, 0, 0);
}

// round-to-nearest-even f32 -> bf16 bits (finite values only)
static __device__ __forceinline__ unsigned short bf16of(float f){
    unsigned int u = __float_as_uint(f);
    unsigned int lsb = (u >> 16) & 1u;
    u += 0x7fffu + lsb;
    return (unsigned short)(u >> 16);
}

// pack two f32 -> two bf16 (round-half-up) via v_perm
static __device__ __forceinline__ unsigned int pk2(float lo, float hi){
    return __builtin_amdgcn_perm(__float_as_uint(hi) + 0x8000u,
                                 __float_as_uint(lo) + 0x8000u, 0x07060302u);
}

// sigmoid-form GELU: x * sigmoid(1.702 x), exp2-folded (5 VALU ops).
static __device__ __forceinline__ float gelu_fast(float x){
    float e = __builtin_amdgcn_exp2f(-2.4554669596f * x);
    return x * __builtin_amdgcn_rcpf(1.0f + e);
}

// ---------------------------------------------------------------- prep
// Pack w1/w2 into MFMA-fragment-major bf16 layouts:
// w1p[(n16*8 + ks)*64 + lane][8]: o = n16*16 + (lane&15), k = ks*32 + (lane>>4)*8 + j
// w2p[(n16*32 + ksg)*64 + lane][8]: w = n16*16 + (lane&15), o = ksg*32 + (lane>>4)*8 + j
__global__ __launch_bounds__(256) void prep_weights(
    const float* __restrict__ w1, const float* __restrict__ w2,
    unsigned short* __restrict__ w1p, unsigned short* __restrict__ w2p)
{
    int t = blockIdx.x * 256 + threadIdx.x;   // 0..65535
    int lane = t & 63;
    if (t < 32768){
        int g = t;
        int ks  = (g >> 6) & 7;
        int n16 = g >> 9;
        int o = n16*16 + (lane & 15);
        int k = ks*32 + (lane >> 4)*8;
        const float* src = w1 + o*256 + k;
        unsigned short* dst = w1p + (size_t)g*8;
        #pragma unroll
        for (int j = 0; j < 8; ++j) dst[j] = bf16of(src[j]);
    } else {
        int g = t - 32768;
        int ksg = (g >> 6) & 31;
        int n16 = g >> 11;
        int n = n16*16 + (lane & 15);
        int k = ksg*32 + (lane >> 4)*8;
        const float* src = w2 + n*1024 + k;
        unsigned short* dst = w2p + (size_t)g*8;
        #pragma unroll
        for (int j = 0; j < 8; ++j) dst[j] = bf16of(src[j]);
    }
}

// ---------------------------------------------------------------- conv + LN (fragment-major output)
// Wave-register LN: wave hs owns output rows 4hs..4hs+3 completely, so LN row
// stats are a 64-lane shuffle reduce — no LDS round-trip, one live barrier pair.
#define CH 16          // output h-rows per block
#define XR (CH + 6)    // input rows incl. halo
#define XWV 66         // float4 chunks per tile row
#define XW 264         // floats per tile row (tile col = gw + 4)

__global__ __launch_bounds__(256) void conv_ln_kernel(
    const float* __restrict__ x, const float* __restrict__ conv_w,
    const float* __restrict__ conv_b, const float* __restrict__ ln_g,
    const float* __restrict__ ln_b, unsigned short* __restrict__ ynormF)
{
    __shared__ float xt[XR * XW];              // 23232 B
    __shared__ unsigned short ytn[CH * 264];   //  8448 B

    const int tid = threadIdx.x;
    const int blk = blockIdx.x;
    const int ht = blk & 15;
    const int c  = (blk >> 4) & 255;
    const int b  = blk >> 12;
    const int h0 = ht * CH;

    const float* xplane = x + (((size_t)(b*256 + c)) << 16);

    // stage x tile: 22 rows x 66 aligned float4 chunks
    for (int i = tid; i < XR*XWV; i += 256){
        int ir = i / XWV;
        int cc = i - ir*XWV;
        int gh = h0 - 3 + ir;
        float4 v = make_float4(0.f, 0.f, 0.f, 0.f);
        if ((unsigned)gh < 256u && (unsigned)(cc - 1) < 64u)
            v = *reinterpret_cast<const float4*>(xplane + gh*256 + (cc - 1)*4);
        *reinterpret_cast<float4*>(&xt[ir*XW + cc*4]) = v;
    }

    float cwr[49];
    #pragma unroll
    for (int i = 0; i < 49; ++i) cwr[i] = conv_w[c*49 + i];
    const float cb = conv_b[c];

    __syncthreads();

    // thread (wq, hs): out cols 4wq..4wq+3, out rows hs*4..hs*4+3 (local)
    const int wq = tid & 63;
    const int hs = tid >> 6;
    float acc[4][4] = {};   // [ro][cc]

    #pragma unroll
    for (int d = 0; d < 10; ++d){
        int ir = hs*4 + d;
        float4 ra = *reinterpret_cast<const float4*>(&xt[ir*XW + wq*4]);
        float4 rb = *reinterpret_cast<const float4*>(&xt[ir*XW + wq*4 + 4]);
        float4 rc = *reinterpret_cast<const float4*>(&xt[ir*XW + wq*4 + 8]);
        float rr[12] = {ra.x, ra.y, ra.z, ra.w, rb.x, rb.y, rb.z, rb.w,
                        rc.x, rc.y, rc.z, rc.w};
        #pragma unroll
        for (int ro = 0; ro < 4; ++ro){
            int dh = d - ro;
            if (dh >= 0 && dh <= 6){
                #pragma unroll
                for (int dw = 0; dw < 7; ++dw){
                    float wv = cwr[dh*7 + dw];
                    #pragma unroll
                    for (int cc = 0; cc < 4; ++cc)
                        acc[ro][cc] = fmaf(rr[cc + dw + 1], wv, acc[ro][cc]);
                }
            }
        }
    }

    // add conv bias now (LN stats need it)
    #pragma unroll
    for (int ro = 0; ro < 4; ++ro)
        #pragma unroll
        for (int cc = 0; cc < 4; ++cc)
            acc[ro][cc] += cb;

    // LN gamma/beta for this thread's 4 cols
    const float4 lgv = *reinterpret_cast<const float4*>(ln_g + wq*4);
    const float4 lbv = *reinterpret_cast<const float4*>(ln_b + wq*4);
    const float lg[4] = {lgv.x, lgv.y, lgv.z, lgv.w};
    const float lb[4] = {lbv.x, lbv.y, lbv.z, lbv.w};

    // per-row LN via 64-lane shuffle reduce; write bf16 to ytn (b64 stores)
    #pragma unroll
    for (int ro = 0; ro < 4; ++ro){
        float s  = acc[ro][0] + acc[ro][1] + acc[ro][2] + acc[ro][3];
        float ss = acc[ro][0]*acc[ro][0] + acc[ro][1]*acc[ro][1]
                 + acc[ro][2]*acc[ro][2] + acc[ro][3]*acc[ro][3];
        #pragma unroll
        for (int off = 32; off > 0; off >>= 1){
            s  += __shfl_xor(s, off);
            ss += __shfl_xor(ss, off);
        }
        float mu  = s * (1.f/256.f);
        float var = ss * (1.f/256.f) - mu*mu;
        float rs  = rsqrtf(var + 1e-5f);
        unsigned int u01, u23;
        {
            float o0 = (acc[ro][0] - mu)*rs*lg[0] + lb[0];
            float o1 = (acc[ro][1] - mu)*rs*lg[1] + lb[1];
            float o2 = (acc[ro][2] - mu)*rs*lg[2] + lb[2];
            float o3 = (acc[ro][3] - mu)*rs*lg[3] + lb[3];
            u01 = (unsigned int)bf16of(o0) | ((unsigned int)bf16of(o1) << 16);
            u23 = (unsigned int)bf16of(o2) | ((unsigned int)bf16of(o3) << 16);
        }
        uint2 pv; pv.x = u01; pv.y = u23;
        *reinterpret_cast<uint2*>(&ytn[(hs*4 + ro)*264 + wq*4]) = pv;
    }

    __syncthreads();

    // fragment-major global write: frag (ks, mf, lane=kg*16+l15, j) =
    // Y[tile*64 + mf*16 + l15][ks*32 + kg*8 + j]; this block owns mf fixed.
    {
        const int l   = tid & 63;
        const int wv  = tid >> 6;
        const int l15w = l & 15, kgw = l >> 4;
        const int tile = (((b*256 + c)*256 + h0) >> 6);
        const int mf = (h0 >> 4) & 3;
        uint4* dst = reinterpret_cast<uint4*>(ynormF) + (size_t)tile*2048;
        #pragma unroll
        for (int it = 0; it < 2; ++it){
            int ks = wv*2 + it;
            uint4 v = *reinterpret_cast<const uint4*>(ytn + l15w*264 + ks*32 + kgw*8);
            dst[(ks*4 + mf)*64 + l] = v;
        }
    }
}

// ---------------------------------------------------------------- fused MLP + transposed-out residual
// 4 waves, M-tile 64, waves split N. o-chunks of 128, Hs double-buffered,
// acc1 double-buffered, rotated regions { gemm2(oc); gelu(oc+1); gemm1(oc+2) }.
// A-tile NOT staged in LDS: all 4 waves read the SAME frag-major 32KB from
// ynormF (coalesced 1KB wave loads, L1/L2-resident across the 8 oc re-reads).
// LDS = Hs dbuf 32KB only -> 4 blocks/CU, 4 waves/SIMD (2x round-11 overlap).
// GEMM1 SWAPPED: mfma(W1,Y) -> P^T[o][m], b64 H-stores. GEMM2 SWAPPED:
// mfma(W2,H) -> Out2^T[w][m] -> barrier-free coalesced epilogue + residual.
// NOTE (R9): do NOT hold the A-tile in REGISTERS — that spills. L1 is the
// right home for it.
__global__ __launch_bounds__(256, 4) void mlp_kernel(
    const unsigned short* __restrict__ ynormF,
    const short* __restrict__ w1p, const short* __restrict__ w2p,
    const float* __restrict__ b1, const float* __restrict__ b2,
    const float* __restrict__ x, float* __restrict__ out)
{
    __shared__ __align__(16) short Hs0[64*128];   // 16KB
    __shared__ __align__(16) short Hs1[64*128];   // 16KB

    const int tid  = threadIdx.x;
    const int lane = tid & 63;
    const int wid  = tid >> 6;
    const int tile = blockIdx.x;
    const int M0 = tile * 64;
    const int b = M0 >> 16, c = (M0 >> 8) & 255, h0 = M0 & 255;

    const int l15  = lane & 15;
    const int kg   = lane >> 4;   // 0..3

    const short8* asrc = reinterpret_cast<const short8*>(ynormF) + (size_t)tile*2048;

    // acc2 initialized with b2 bias: acc2[mf][nfi][r] -> w = (wid*4+nfi)*16+kg*4+r
    f32x4 acc2[4][4];
    #pragma unroll
    for (int nfi = 0; nfi < 4; ++nfi){
        float4 bv = *reinterpret_cast<const float4*>(b2 + (wid*4 + nfi)*16 + kg*4);
        f32x4 b4 = {bv.x, bv.y, bv.z, bv.w};
        #pragma unroll
        for (int mf = 0; mf < 4; ++mf) acc2[mf][nfi] = b4;
    }

    f32x4 accA[4][2], accB[4][2];
    short8 pw2[4];

    // GEMM1 for o-chunk oc (128 cols), SWAPPED operands; A direct from global:
    // acc1[mf][nfi][r] = P[o = (oc*8+wid*2+nfi)*16 + kg*4 + r][m = mf*16 + l15] + b1[o]
    auto gemm1 = [&](int oc, f32x4 (&acc1)[4][2]){
        #pragma unroll
        for (int nfi = 0; nfi < 2; ++nfi){
            float4 bv = *reinterpret_cast<const float4*>(
                b1 + oc*128 + (wid*2 + nfi)*16 + kg*4);
            f32x4 bi = {bv.x, bv.y, bv.z, bv.w};
            #pragma unroll
            for (int mf = 0; mf < 4; ++mf) acc1[mf][nfi] = bi;
        }
        #pragma unroll
        for (int ks = 0; ks < 8; ++ks){
            short8 afr[4], bfr[2];
            #pragma unroll
            for (int mf = 0; mf < 4; ++mf)
                afr[mf] = asrc[(ks*4 + mf)*64 + lane];
            #pragma unroll
            for (int nfi = 0; nfi < 2; ++nfi)
                bfr[nfi] = *reinterpret_cast<const short8*>(
                    w1p + ((size_t)(((oc*8 + wid*2 + nfi)*8 + ks)*64 + lane)) * 8);
            #pragma unroll
            for (int mf = 0; mf < 4; ++mf)
                #pragma unroll
                for (int nfi = 0; nfi < 2; ++nfi)
                    acc1[mf][nfi] = mfma16(bfr[nfi], afr[mf], acc1[mf][nfi]);
        }
    };

    // GELU + pack -> Hb: one b64 store per (nfi, mf): H[m][o..o+3]
    // byte layout identical to gemm2's read: chunk8 ^= (m&7)
    auto gelu_store = [&](f32x4 (&acc1)[4][2], short* Hb){
        #pragma unroll
        for (int nfi = 0; nfi < 2; ++nfi){
            int chunkbase = (wid*2 + nfi)*2 + (kg >> 1);   // o>>3
            int osub = (kg & 1) << 2;                      // o&7 (4-aligned)
            #pragma unroll
            for (int mf = 0; mf < 4; ++mf){
                int m = mf*16 + l15;
                uint2 pv;
                pv.x = pk2(gelu_fast(acc1[mf][nfi][0]), gelu_fast(acc1[mf][nfi][1]));
                pv.y = pk2(gelu_fast(acc1[mf][nfi][2]), gelu_fast(acc1[mf][nfi][3]));
                *reinterpret_cast<uint2*>(
                    Hb + m*128 + ((chunkbase ^ (m & 7)) << 3) + osub) = pv;
            }
        }
    };

    auto prefetch_pw2 = [&](int oc){
        #pragma unroll
        for (int nfi = 0; nfi < 4; ++nfi)
            pw2[nfi] = *reinterpret_cast<const short8*>(
                w2p + ((size_t)(((wid*4 + nfi)*32 + oc*4 + 0)*64 + lane)) * 8);
    };

    // GEMM2 partial (SWAPPED): Out2^T[w][m] += W2-slice @ H-chunk^T
    auto gemm2f = [&](int oc, short* Hb){
        #pragma unroll
        for (int ks = 0; ks < 4; ++ks){
            short8 hfr[4], wfr[4];
            #pragma unroll
            for (int mf = 0; mf < 4; ++mf){
                int row = mf*16 + l15;
                hfr[mf] = *reinterpret_cast<const short8*>(
                    Hb + row*128 + (((ks*4 + kg) ^ (l15 & 7)) << 3));
            }
            if (ks == 0){
                #pragma unroll
                for (int nfi = 0; nfi < 4; ++nfi) wfr[nfi] = pw2[nfi];
            } else {
                #pragma unroll
                for (int nfi = 0; nfi < 4; ++nfi)
                    wfr[nfi] = *reinterpret_cast<const short8*>(
                        w2p + ((size_t)(((wid*4 + nfi)*32 + oc*4 + ks)*64 + lane)) * 8);
            }
            #pragma unroll
            for (int mf = 0; mf < 4; ++mf)
                #pragma unroll
                for (int nfi = 0; nfi < 4; ++nfi)
                    acc2[mf][nfi] = mfma16(wfr[nfi], hfr[mf], acc2[mf][nfi]);
        }
    };

    // prologue: fill the 2-deep pipeline
    gemm1(0, accA);
    gelu_store(accA, Hs0);
    gemm1(1, accB);
    prefetch_pw2(0);
    __syncthreads();

    #pragma unroll
    for (int oc = 0; oc < 8; ++oc){
        short* Hcur = (oc & 1) ? Hs1 : Hs0;
        gemm2f(oc, Hcur);
        if (oc < 7){
            f32x4 (&accR)[4][2] = ((oc + 1) & 1) ? accB : accA;
            gelu_store(accR, (oc & 1) ? Hs0 : Hs1);
        }
        if (oc < 6){
            f32x4 (&accW)[4][2] = ((oc + 2) & 1) ? accB : accA;
            gemm1(oc + 2, accW);
        }
        if (oc < 7){
            prefetch_pw2(oc + 1);
            __syncthreads();
        }
    }

    // ---- barrier-free epilogue (bias already in acc2):
    // acc2[mf][nfi][r] = Out2^T[w = (wid*4+nfi)*16 + kg*4 + r][m = mf*16 + l15]
    #pragma unroll
    for (int nfi = 0; nfi < 4; ++nfi){
        #pragma unroll
        for (int r = 0; r < 4; ++r){
            int w = (wid*4 + nfi)*16 + kg*4 + r;
            size_t base = ((size_t)b << 24) + ((size_t)w << 16) + (c << 8) + h0 + l15;
            #pragma unroll
            for (int mf = 0; mf < 4; ++mf){
                size_t o = base + mf*16;
                out[o] = acc2[mf][nfi][r] + x[o];
            }
        }
    }
}

// ---------------------------------------------------------------- launch
extern "C" void kernel_launch(void* const* d_in, const int* in_sizes, int n_in,
                              void* d_out, int out_size, void* d_ws, size_t ws_size,
                              hipStream_t stream)
{
    const float* x      = (const float*)d_in[0];
    const float* conv_w = (const float*)d_in[1];
    const float* conv_b = (const float*)d_in[2];
    const float* ln_g   = (const float*)d_in[3];
    const float* ln_b   = (const float*)d_in[4];
    const float* w1     = (const float*)d_in[5];
    const float* b1     = (const float*)d_in[6];
    const float* w2     = (const float*)d_in[7];
    const float* b2     = (const float*)d_in[8];
    float* out = (float*)d_out;

    unsigned short* ynormF = (unsigned short*)d_ws;                         // 67,108,864 B
    unsigned short* w1p    = (unsigned short*)((char*)d_ws + 67108864);     //    524,288 B
    unsigned short* w2p    = (unsigned short*)((char*)d_ws + 67108864 + 524288);

    hipLaunchKernelGGL(prep_weights, dim3(256), dim3(256), 0, stream, w1, w2, w1p, w2p);
    hipLaunchKernelGGL(conv_ln_kernel, dim3(8192), dim3(256), 0, stream,
                       x, conv_w, conv_b, ln_g, ln_b, ynormF);
    hipLaunchKernelGGL(mlp_kernel, dim3(2048), dim3(256), 0, stream,
                       ynormF, (const short*)w1p, (const short*)w2p, b1, b2, x, out);
}

// Round 14
// 268.171 us; speedup vs baseline: 2.3826x; 2.3826x over previous
//
#include <hip/hip_runtime.h>
#include <hip/hip_bf16.h>
#include <math.h>

using short8 = __attribute__((ext_vector_type(8))) short;
using f32x4  = __attribute__((ext_vector_type(4))) float;

static __device__ __forceinline__ f32x4 mfma16(short8 a, short8 b, f32x4 c){
    return __builtin_amdgcn_mfma_f32_16x16x32_bf16(a, b, c, 0, 0, 0);
}

// round-to-nearest-even f32 -> bf16 bits (finite values only)
static __device__ __forceinline__ unsigned short bf16of(float f){
    unsigned int u = __float_as_uint(f);
    unsigned int lsb = (u >> 16) & 1u;
    u += 0x7fffu + lsb;
    return (unsigned short)(u >> 16);
}

// pack two f32 -> two bf16 (round-half-up) via v_perm
static __device__ __forceinline__ unsigned int pk2(float lo, float hi){
    return __builtin_amdgcn_perm(__float_as_uint(hi) + 0x8000u,
                                 __float_as_uint(lo) + 0x8000u, 0x07060302u);
}

// sigmoid-form GELU: x * sigmoid(1.702 x), exp2-folded (5 VALU ops).
static __device__ __forceinline__ float gelu_fast(float x){
    float e = __builtin_amdgcn_exp2f(-2.4554669596f * x);
    return x * __builtin_amdgcn_rcpf(1.0f + e);
}

// ---------------------------------------------------------------- prep
// Pack w1/w2 into MFMA-fragment-major bf16 layouts:
// w1p[(n16*8 + ks)*64 + lane][8]: o = n16*16 + (lane&15), k = ks*32 + (lane>>4)*8 + j
// w2p[(n16*32 + ksg)*64 + lane][8]: w = n16*16 + (lane&15), o = ksg*32 + (lane>>4)*8 + j
__global__ __launch_bounds__(256) void prep_weights(
    const float* __restrict__ w1, const float* __restrict__ w2,
    unsigned short* __restrict__ w1p, unsigned short* __restrict__ w2p)
{
    int t = blockIdx.x * 256 + threadIdx.x;   // 0..65535
    int lane = t & 63;
    if (t < 32768){
        int g = t;
        int ks  = (g >> 6) & 7;
        int n16 = g >> 9;
        int o = n16*16 + (lane & 15);
        int k = ks*32 + (lane >> 4)*8;
        const float* src = w1 + o*256 + k;
        unsigned short* dst = w1p + (size_t)g*8;
        #pragma unroll
        for (int j = 0; j < 8; ++j) dst[j] = bf16of(src[j]);
    } else {
        int g = t - 32768;
        int ksg = (g >> 6) & 31;
        int n16 = g >> 11;
        int n = n16*16 + (lane & 15);
        int k = ksg*32 + (lane >> 4)*8;
        const float* src = w2 + n*1024 + k;
        unsigned short* dst = w2p + (size_t)g*8;
        #pragma unroll
        for (int j = 0; j < 8; ++j) dst[j] = bf16of(src[j]);
    }
}

// ---------------------------------------------------------------- conv + LN (fragment-major output)
// Wave-register LN: wave hs owns output rows 4hs..4hs+3 completely, so LN row
// stats are a 64-lane shuffle reduce — no LDS round-trip, one live barrier pair.
#define CH 16          // output h-rows per block
#define XR (CH + 6)    // input rows incl. halo
#define XWV 66         // float4 chunks per tile row
#define XW 264         // floats per tile row (tile col = gw + 4)

__global__ __launch_bounds__(256) void conv_ln_kernel(
    const float* __restrict__ x, const float* __restrict__ conv_w,
    const float* __restrict__ conv_b, const float* __restrict__ ln_g,
    const float* __restrict__ ln_b, unsigned short* __restrict__ ynormF)
{
    __shared__ float xt[XR * XW];              // 23232 B
    __shared__ unsigned short ytn[CH * 264];   //  8448 B

    const int tid = threadIdx.x;
    const int blk = blockIdx.x;
    const int ht = blk & 15;
    const int c  = (blk >> 4) & 255;
    const int b  = blk >> 12;
    const int h0 = ht * CH;

    const float* xplane = x + (((size_t)(b*256 + c)) << 16);

    // stage x tile: 22 rows x 66 aligned float4 chunks
    for (int i = tid; i < XR*XWV; i += 256){
        int ir = i / XWV;
        int cc = i - ir*XWV;
        int gh = h0 - 3 + ir;
        float4 v = make_float4(0.f, 0.f, 0.f, 0.f);
        if ((unsigned)gh < 256u && (unsigned)(cc - 1) < 64u)
            v = *reinterpret_cast<const float4*>(xplane + gh*256 + (cc - 1)*4);
        *reinterpret_cast<float4*>(&xt[ir*XW + cc*4]) = v;
    }

    float cwr[49];
    #pragma unroll
    for (int i = 0; i < 49; ++i) cwr[i] = conv_w[c*49 + i];
    const float cb = conv_b[c];

    __syncthreads();

    // thread (wq, hs): out cols 4wq..4wq+3, out rows hs*4..hs*4+3 (local)
    const int wq = tid & 63;
    const int hs = tid >> 6;
    float acc[4][4] = {};   // [ro][cc]

    #pragma unroll
    for (int d = 0; d < 10; ++d){
        int ir = hs*4 + d;
        float4 ra = *reinterpret_cast<const float4*>(&xt[ir*XW + wq*4]);
        float4 rb = *reinterpret_cast<const float4*>(&xt[ir*XW + wq*4 + 4]);
        float4 rc = *reinterpret_cast<const float4*>(&xt[ir*XW + wq*4 + 8]);
        float rr[12] = {ra.x, ra.y, ra.z, ra.w, rb.x, rb.y, rb.z, rb.w,
                        rc.x, rc.y, rc.z, rc.w};
        #pragma unroll
        for (int ro = 0; ro < 4; ++ro){
            int dh = d - ro;
            if (dh >= 0 && dh <= 6){
                #pragma unroll
                for (int dw = 0; dw < 7; ++dw){
                    float wv = cwr[dh*7 + dw];
                    #pragma unroll
                    for (int cc = 0; cc < 4; ++cc)
                        acc[ro][cc] = fmaf(rr[cc + dw + 1], wv, acc[ro][cc]);
                }
            }
        }
    }

    // add conv bias now (LN stats need it)
    #pragma unroll
    for (int ro = 0; ro < 4; ++ro)
        #pragma unroll
        for (int cc = 0; cc < 4; ++cc)
            acc[ro][cc] += cb;

    // LN gamma/beta for this thread's 4 cols
    const float4 lgv = *reinterpret_cast<const float4*>(ln_g + wq*4);
    const float4 lbv = *reinterpret_cast<const float4*>(ln_b + wq*4);
    const float lg[4] = {lgv.x, lgv.y, lgv.z, lgv.w};
    const float lb[4] = {lbv.x, lbv.y, lbv.z, lbv.w};

    // per-row LN via 64-lane shuffle reduce; write bf16 to ytn (b64 stores)
    #pragma unroll
    for (int ro = 0; ro < 4; ++ro){
        float s  = acc[ro][0] + acc[ro][1] + acc[ro][2] + acc[ro][3];
        float ss = acc[ro][0]*acc[ro][0] + acc[ro][1]*acc[ro][1]
                 + acc[ro][2]*acc[ro][2] + acc[ro][3]*acc[ro][3];
        #pragma unroll
        for (int off = 32; off > 0; off >>= 1){
            s  += __shfl_xor(s, off);
            ss += __shfl_xor(ss, off);
        }
        float mu  = s * (1.f/256.f);
        float var = ss * (1.f/256.f) - mu*mu;
        float rs  = rsqrtf(var + 1e-5f);
        unsigned int u01, u23;
        {
            float o0 = (acc[ro][0] - mu)*rs*lg[0] + lb[0];
            float o1 = (acc[ro][1] - mu)*rs*lg[1] + lb[1];
            float o2 = (acc[ro][2] - mu)*rs*lg[2] + lb[2];
            float o3 = (acc[ro][3] - mu)*rs*lg[3] + lb[3];
            u01 = (unsigned int)bf16of(o0) | ((unsigned int)bf16of(o1) << 16);
            u23 = (unsigned int)bf16of(o2) | ((unsigned int)bf16of(o3) << 16);
        }
        uint2 pv; pv.x = u01; pv.y = u23;
        *reinterpret_cast<uint2*>(&ytn[(hs*4 + ro)*264 + wq*4]) = pv;
    }

    __syncthreads();

    // fragment-major global write: frag (ks, mf, lane=kg*16+l15, j) =
    // Y[tile*64 + mf*16 + l15][ks*32 + kg*8 + j]; this block owns mf fixed.
    {
        const int l   = tid & 63;
        const int wv  = tid >> 6;
        const int l15w = l & 15, kgw = l >> 4;
        const int tile = (((b*256 + c)*256 + h0) >> 6);
        const int mf = (h0 >> 4) & 3;
        uint4* dst = reinterpret_cast<uint4*>(ynormF) + (size_t)tile*2048;
        #pragma unroll
        for (int it = 0; it < 2; ++it){
            int ks = wv*2 + it;
            uint4 v = *reinterpret_cast<const uint4*>(ytn + l15w*264 + ks*32 + kgw*8);
            dst[(ks*4 + mf)*64 + l] = v;
        }
    }
}

// ---------------------------------------------------------------- fused MLP + transposed-out residual
// 4 waves, M-tile 64, waves split N. o-chunks of 128, Hs double-buffered,
// acc1 double-buffered, rotated regions { gemm2(oc); gelu(oc+1); gemm1(oc+2) }.
// A-tile NOT staged in LDS: all 4 waves read the SAME frag-major 32KB from
// ynormF (coalesced 1KB wave loads, L2-resident across the 8 oc re-reads).
// LDS = Hs dbuf 32KB only; VGPR ~128 (natural) -> 4 blocks/CU, 4 waves/SIMD.
// R13 lesson: launch_bounds(256,4) forced VGPR=64 -> catastrophic spill; the
// correct bound is (256,2) letting the allocator keep ~128 and occupancy rise
// via the LDS reduction alone.
// GEMM1 SWAPPED: mfma(W1,Y) -> P^T[o][m], b64 H-stores. GEMM2 SWAPPED:
// mfma(W2,H) -> Out2^T[w][m] -> barrier-free coalesced epilogue + residual.
__global__ __launch_bounds__(256, 2) void mlp_kernel(
    const unsigned short* __restrict__ ynormF,
    const short* __restrict__ w1p, const short* __restrict__ w2p,
    const float* __restrict__ b1, const float* __restrict__ b2,
    const float* __restrict__ x, float* __restrict__ out)
{
    __shared__ __align__(16) short Hs0[64*128];   // 16KB
    __shared__ __align__(16) short Hs1[64*128];   // 16KB

    const int tid  = threadIdx.x;
    const int lane = tid & 63;
    const int wid  = tid >> 6;
    const int tile = blockIdx.x;
    const int M0 = tile * 64;
    const int b = M0 >> 16, c = (M0 >> 8) & 255, h0 = M0 & 255;

    const int l15  = lane & 15;
    const int kg   = lane >> 4;   // 0..3

    const short8* asrc = reinterpret_cast<const short8*>(ynormF) + (size_t)tile*2048;

    // acc2 initialized with b2 bias: acc2[mf][nfi][r] -> w = (wid*4+nfi)*16+kg*4+r
    f32x4 acc2[4][4];
    #pragma unroll
    for (int nfi = 0; nfi < 4; ++nfi){
        float4 bv = *reinterpret_cast<const float4*>(b2 + (wid*4 + nfi)*16 + kg*4);
        f32x4 b4 = {bv.x, bv.y, bv.z, bv.w};
        #pragma unroll
        for (int mf = 0; mf < 4; ++mf) acc2[mf][nfi] = b4;
    }

    f32x4 accA[4][2], accB[4][2];
    short8 pw2[4];

    // GEMM1 for o-chunk oc (128 cols), SWAPPED operands; A direct from global:
    // acc1[mf][nfi][r] = P[o = (oc*8+wid*2+nfi)*16 + kg*4 + r][m = mf*16 + l15] + b1[o]
    auto gemm1 = [&](int oc, f32x4 (&acc1)[4][2]){
        #pragma unroll
        for (int nfi = 0; nfi < 2; ++nfi){
            float4 bv = *reinterpret_cast<const float4*>(
                b1 + oc*128 + (wid*2 + nfi)*16 + kg*4);
            f32x4 bi = {bv.x, bv.y, bv.z, bv.w};
            #pragma unroll
            for (int mf = 0; mf < 4; ++mf) acc1[mf][nfi] = bi;
        }
        #pragma unroll
        for (int ks = 0; ks < 8; ++ks){
            short8 afr[4], bfr[2];
            #pragma unroll
            for (int mf = 0; mf < 4; ++mf)
                afr[mf] = asrc[(ks*4 + mf)*64 + lane];
            #pragma unroll
            for (int nfi = 0; nfi < 2; ++nfi)
                bfr[nfi] = *reinterpret_cast<const short8*>(
                    w1p + ((size_t)(((oc*8 + wid*2 + nfi)*8 + ks)*64 + lane)) * 8);
            #pragma unroll
            for (int mf = 0; mf < 4; ++mf)
                #pragma unroll
                for (int nfi = 0; nfi < 2; ++nfi)
                    acc1[mf][nfi] = mfma16(bfr[nfi], afr[mf], acc1[mf][nfi]);
        }
    };

    // GELU + pack -> Hb: one b64 store per (nfi, mf): H[m][o..o+3]
    // byte layout identical to gemm2's read: chunk8 ^= (m&7)
    auto gelu_store = [&](f32x4 (&acc1)[4][2], short* Hb){
        #pragma unroll
        for (int nfi = 0; nfi < 2; ++nfi){
            int chunkbase = (wid*2 + nfi)*2 + (kg >> 1);   // o>>3
            int osub = (kg & 1) << 2;                      // o&7 (4-aligned)
            #pragma unroll
            for (int mf = 0; mf < 4; ++mf){
                int m = mf*16 + l15;
                uint2 pv;
                pv.x = pk2(gelu_fast(acc1[mf][nfi][0]), gelu_fast(acc1[mf][nfi][1]));
                pv.y = pk2(gelu_fast(acc1[mf][nfi][2]), gelu_fast(acc1[mf][nfi][3]));
                *reinterpret_cast<uint2*>(
                    Hb + m*128 + ((chunkbase ^ (m & 7)) << 3) + osub) = pv;
            }
        }
    };

    auto prefetch_pw2 = [&](int oc){
        #pragma unroll
        for (int nfi = 0; nfi < 4; ++nfi)
            pw2[nfi] = *reinterpret_cast<const short8*>(
                w2p + ((size_t)(((wid*4 + nfi)*32 + oc*4 + 0)*64 + lane)) * 8);
    };

    // GEMM2 partial (SWAPPED): Out2^T[w][m] += W2-slice @ H-chunk^T
    auto gemm2f = [&](int oc, short* Hb){
        #pragma unroll
        for (int ks = 0; ks < 4; ++ks){
            short8 hfr[4], wfr[4];
            #pragma unroll
            for (int mf = 0; mf < 4; ++mf){
                int row = mf*16 + l15;
                hfr[mf] = *reinterpret_cast<const short8*>(
                    Hb + row*128 + (((ks*4 + kg) ^ (l15 & 7)) << 3));
            }
            if (ks == 0){
                #pragma unroll
                for (int nfi = 0; nfi < 4; ++nfi) wfr[nfi] = pw2[nfi];
            } else {
                #pragma unroll
                for (int nfi = 0; nfi < 4; ++nfi)
                    wfr[nfi] = *reinterpret_cast<const short8*>(
                        w2p + ((size_t)(((wid*4 + nfi)*32 + oc*4 + ks)*64 + lane)) * 8);
            }
            #pragma unroll
            for (int mf = 0; mf < 4; ++mf)
                #pragma unroll
                for (int nfi = 0; nfi < 4; ++nfi)
                    acc2[mf][nfi] = mfma16(wfr[nfi], hfr[mf], acc2[mf][nfi]);
        }
    };

    // prologue: fill the 2-deep pipeline
    gemm1(0, accA);
    gelu_store(accA, Hs0);
    gemm1(1, accB);
    prefetch_pw2(0);
    __syncthreads();

    #pragma unroll
    for (int oc = 0; oc < 8; ++oc){
        short* Hcur = (oc & 1) ? Hs1 : Hs0;
        gemm2f(oc, Hcur);
        if (oc < 7){
            f32x4 (&accR)[4][2] = ((oc + 1) & 1) ? accB : accA;
            gelu_store(accR, (oc & 1) ? Hs0 : Hs1);
        }
        if (oc < 6){
            f32x4 (&accW)[4][2] = ((oc + 2) & 1) ? accB : accA;
            gemm1(oc + 2, accW);
        }
        if (oc < 7){
            prefetch_pw2(oc + 1);
            __syncthreads();
        }
    }

    // ---- barrier-free epilogue (bias already in acc2):
    // acc2[mf][nfi][r] = Out2^T[w = (wid*4+nfi)*16 + kg*4 + r][m = mf*16 + l15]
    #pragma unroll
    for (int nfi = 0; nfi < 4; ++nfi){
        #pragma unroll
        for (int r = 0; r < 4; ++r){
            int w = (wid*4 + nfi)*16 + kg*4 + r;
            size_t base = ((size_t)b << 24) + ((size_t)w << 16) + (c << 8) + h0 + l15;
            #pragma unroll
            for (int mf = 0; mf < 4; ++mf){
                size_t o = base + mf*16;
                out[o] = acc2[mf][nfi][r] + x[o];
            }
        }
    }
}

// ---------------------------------------------------------------- launch
extern "C" void kernel_launch(void* const* d_in, const int* in_sizes, int n_in,
                              void* d_out, int out_size, void* d_ws, size_t ws_size,
                              hipStream_t stream)
{
    const float* x      = (const float*)d_in[0];
    const float* conv_w = (const float*)d_in[1];
    const float* conv_b = (const float*)d_in[2];
    const float* ln_g   = (const float*)d_in[3];
    const float* ln_b   = (const float*)d_in[4];
    const float* w1     = (const float*)d_in[5];
    const float* b1     = (const float*)d_in[6];
    const float* w2     = (const float*)d_in[7];
    const float* b2     = (const float*)d_in[8];
    float* out = (float*)d_out;

    unsigned short* ynormF = (unsigned short*)d_ws;                         // 67,108,864 B
    unsigned short* w1p    = (unsigned short*)((char*)d_ws + 67108864);     //    524,288 B
    unsigned short* w2p    = (unsigned short*)((char*)d_ws + 67108864 + 524288);

    hipLaunchKernelGGL(prep_weights, dim3(256), dim3(256), 0, stream, w1, w2, w1p, w2p);
    hipLaunchKernelGGL(conv_ln_kernel, dim3(8192), dim3(256), 0, stream,
                       x, conv_w, conv_b, ln_g, ln_b, ynormF);
    hipLaunchKernelGGL(mlp_kernel, dim3(2048), dim3(256), 0, stream,
                       ynormF, (const short*)w1p, (const short*)w2p, b1, b2, x, out);
}

// Round 15
// 238.600 us; speedup vs baseline: 2.6779x; 1.1239x over previous
//
#include <hip/hip_runtime.h>
#include <hip/hip_bf16.h>
#include <math.h>

using short8 = __attribute__((ext_vector_type(8))) short;
using f32x4  = __attribute__((ext_vector_type(4))) float;

static __device__ __forceinline__ f32x4 mfma16(short8 a, short8 b, f32x4 c){
    return __builtin_amdgcn_mfma_f32_16x16x32_bf16(a, b, c, 0, 0, 0);
}

// LDS-only barrier: drains lgkmcnt (ds ordering) but leaves global loads in
// flight across the barrier (T4). Safe here: barriers only order Hs (LDS);
// register-destined global loads are ordered by compiler use-site waitcnts.
static __device__ __forceinline__ void barrier_lds(){
    asm volatile("s_waitcnt lgkmcnt(0)" ::: "memory");
    __builtin_amdgcn_s_barrier();
}

// round-to-nearest-even f32 -> bf16 bits (finite values only)
static __device__ __forceinline__ unsigned short bf16of(float f){
    unsigned int u = __float_as_uint(f);
    unsigned int lsb = (u >> 16) & 1u;
    u += 0x7fffu + lsb;
    return (unsigned short)(u >> 16);
}

// pack two f32 -> two bf16 (round-half-up) via v_perm
static __device__ __forceinline__ unsigned int pk2(float lo, float hi){
    return __builtin_amdgcn_perm(__float_as_uint(hi) + 0x8000u,
                                 __float_as_uint(lo) + 0x8000u, 0x07060302u);
}

// sigmoid-form GELU: x * sigmoid(1.702 x), exp2-folded (5 VALU ops).
static __device__ __forceinline__ float gelu_fast(float x){
    float e = __builtin_amdgcn_exp2f(-2.4554669596f * x);
    return x * __builtin_amdgcn_rcpf(1.0f + e);
}

// ---------------------------------------------------------------- prep
// Pack w1/w2 into MFMA-fragment-major bf16 layouts:
// w1p[(n16*8 + ks)*64 + lane][8]: o = n16*16 + (lane&15), k = ks*32 + (lane>>4)*8 + j
// w2p[(n16*32 + ksg)*64 + lane][8]: w = n16*16 + (lane&15), o = ksg*32 + (lane>>4)*8 + j
__global__ __launch_bounds__(256) void prep_weights(
    const float* __restrict__ w1, const float* __restrict__ w2,
    unsigned short* __restrict__ w1p, unsigned short* __restrict__ w2p)
{
    int t = blockIdx.x * 256 + threadIdx.x;   // 0..65535
    int lane = t & 63;
    if (t < 32768){
        int g = t;
        int ks  = (g >> 6) & 7;
        int n16 = g >> 9;
        int o = n16*16 + (lane & 15);
        int k = ks*32 + (lane >> 4)*8;
        const float* src = w1 + o*256 + k;
        unsigned short* dst = w1p + (size_t)g*8;
        #pragma unroll
        for (int j = 0; j < 8; ++j) dst[j] = bf16of(src[j]);
    } else {
        int g = t - 32768;
        int ksg = (g >> 6) & 31;
        int n16 = g >> 11;
        int n = n16*16 + (lane & 15);
        int k = ksg*32 + (lane >> 4)*8;
        const float* src = w2 + n*1024 + k;
        unsigned short* dst = w2p + (size_t)g*8;
        #pragma unroll
        for (int j = 0; j < 8; ++j) dst[j] = bf16of(src[j]);
    }
}

// ---------------------------------------------------------------- conv + LN (fragment-major output)
// Wave-register LN: wave hs owns output rows 4hs..4hs+3 completely, so LN row
// stats are a 64-lane shuffle reduce — no LDS round-trip, one live barrier pair.
#define CH 16          // output h-rows per block
#define XR (CH + 6)    // input rows incl. halo
#define XWV 66         // float4 chunks per tile row
#define XW 264         // floats per tile row (tile col = gw + 4)

__global__ __launch_bounds__(256) void conv_ln_kernel(
    const float* __restrict__ x, const float* __restrict__ conv_w,
    const float* __restrict__ conv_b, const float* __restrict__ ln_g,
    const float* __restrict__ ln_b, unsigned short* __restrict__ ynormF)
{
    __shared__ float xt[XR * XW];              // 23232 B
    __shared__ unsigned short ytn[CH * 264];   //  8448 B

    const int tid = threadIdx.x;
    const int blk = blockIdx.x;
    const int ht = blk & 15;
    const int c  = (blk >> 4) & 255;
    const int b  = blk >> 12;
    const int h0 = ht * CH;

    const float* xplane = x + (((size_t)(b*256 + c)) << 16);

    // stage x tile: 22 rows x 66 aligned float4 chunks
    for (int i = tid; i < XR*XWV; i += 256){
        int ir = i / XWV;
        int cc = i - ir*XWV;
        int gh = h0 - 3 + ir;
        float4 v = make_float4(0.f, 0.f, 0.f, 0.f);
        if ((unsigned)gh < 256u && (unsigned)(cc - 1) < 64u)
            v = *reinterpret_cast<const float4*>(xplane + gh*256 + (cc - 1)*4);
        *reinterpret_cast<float4*>(&xt[ir*XW + cc*4]) = v;
    }

    float cwr[49];
    #pragma unroll
    for (int i = 0; i < 49; ++i) cwr[i] = conv_w[c*49 + i];
    const float cb = conv_b[c];

    __syncthreads();

    // thread (wq, hs): out cols 4wq..4wq+3, out rows hs*4..hs*4+3 (local)
    const int wq = tid & 63;
    const int hs = tid >> 6;
    float acc[4][4] = {};   // [ro][cc]

    #pragma unroll
    for (int d = 0; d < 10; ++d){
        int ir = hs*4 + d;
        float4 ra = *reinterpret_cast<const float4*>(&xt[ir*XW + wq*4]);
        float4 rb = *reinterpret_cast<const float4*>(&xt[ir*XW + wq*4 + 4]);
        float4 rc = *reinterpret_cast<const float4*>(&xt[ir*XW + wq*4 + 8]);
        float rr[12] = {ra.x, ra.y, ra.z, ra.w, rb.x, rb.y, rb.z, rb.w,
                        rc.x, rc.y, rc.z, rc.w};
        #pragma unroll
        for (int ro = 0; ro < 4; ++ro){
            int dh = d - ro;
            if (dh >= 0 && dh <= 6){
                #pragma unroll
                for (int dw = 0; dw < 7; ++dw){
                    float wv = cwr[dh*7 + dw];
                    #pragma unroll
                    for (int cc = 0; cc < 4; ++cc)
                        acc[ro][cc] = fmaf(rr[cc + dw + 1], wv, acc[ro][cc]);
                }
            }
        }
    }

    // add conv bias now (LN stats need it)
    #pragma unroll
    for (int ro = 0; ro < 4; ++ro)
        #pragma unroll
        for (int cc = 0; cc < 4; ++cc)
            acc[ro][cc] += cb;

    // LN gamma/beta for this thread's 4 cols
    const float4 lgv = *reinterpret_cast<const float4*>(ln_g + wq*4);
    const float4 lbv = *reinterpret_cast<const float4*>(ln_b + wq*4);
    const float lg[4] = {lgv.x, lgv.y, lgv.z, lgv.w};
    const float lb[4] = {lbv.x, lbv.y, lbv.z, lbv.w};

    // per-row LN via 64-lane shuffle reduce; write bf16 to ytn (b64 stores)
    #pragma unroll
    for (int ro = 0; ro < 4; ++ro){
        float s  = acc[ro][0] + acc[ro][1] + acc[ro][2] + acc[ro][3];
        float ss = acc[ro][0]*acc[ro][0] + acc[ro][1]*acc[ro][1]
                 + acc[ro][2]*acc[ro][2] + acc[ro][3]*acc[ro][3];
        #pragma unroll
        for (int off = 32; off > 0; off >>= 1){
            s  += __shfl_xor(s, off);
            ss += __shfl_xor(ss, off);
        }
        float mu  = s * (1.f/256.f);
        float var = ss * (1.f/256.f) - mu*mu;
        float rs  = rsqrtf(var + 1e-5f);
        unsigned int u01, u23;
        {
            float o0 = (acc[ro][0] - mu)*rs*lg[0] + lb[0];
            float o1 = (acc[ro][1] - mu)*rs*lg[1] + lb[1];
            float o2 = (acc[ro][2] - mu)*rs*lg[2] + lb[2];
            float o3 = (acc[ro][3] - mu)*rs*lg[3] + lb[3];
            u01 = (unsigned int)bf16of(o0) | ((unsigned int)bf16of(o1) << 16);
            u23 = (unsigned int)bf16of(o2) | ((unsigned int)bf16of(o3) << 16);
        }
        uint2 pv; pv.x = u01; pv.y = u23;
        *reinterpret_cast<uint2*>(&ytn[(hs*4 + ro)*264 + wq*4]) = pv;
    }

    __syncthreads();

    // fragment-major global write: frag (ks, mf, lane=kg*16+l15, j) =
    // Y[tile*64 + mf*16 + l15][ks*32 + kg*8 + j]; this block owns mf fixed.
    {
        const int l   = tid & 63;
        const int wv  = tid >> 6;
        const int l15w = l & 15, kgw = l >> 4;
        const int tile = (((b*256 + c)*256 + h0) >> 6);
        const int mf = (h0 >> 4) & 3;
        uint4* dst = reinterpret_cast<uint4*>(ynormF) + (size_t)tile*2048;
        #pragma unroll
        for (int it = 0; it < 2; ++it){
            int ks = wv*2 + it;
            uint4 v = *reinterpret_cast<const uint4*>(ytn + l15w*264 + ks*32 + kgw*8);
            dst[(ks*4 + mf)*64 + l] = v;
        }
    }
}

// ---------------------------------------------------------------- fused MLP + transposed-out residual
// (R11 structure — best measured 162 us — with LDS-only barriers (T4):
// weight loads stay in flight across the 8 region barriers instead of being
// vmcnt(0)-drained by __syncthreads.)
// 4 waves, M-tile 64, waves split N. o-chunks of 128, Hs double-buffered,
// acc1 double-buffered, rotated regions { gemm2(oc); gelu(oc+1); gemm1(oc+2) }.
// A staged in LDS frag-major (conflict-free lane-contiguous ds_read_b128).
// GEMM1 SWAPPED: mfma(W1,Y) -> P^T[o][m], b64 H-stores. GEMM2 SWAPPED:
// mfma(W2,H) -> Out2^T[w][m] -> barrier-free coalesced epilogue + residual.
// R9 lesson: A-tile in registers spills. R13 lesson: launch_bounds(,4)
// forces VGPR=64 -> spill. R14 lesson: occupancy is register-walled at
// 2 waves/SIMD (unified VGPR+AGPR ~256/thread); A-from-L1 regresses.
__global__ __launch_bounds__(256, 2) void mlp_kernel(
    const unsigned short* __restrict__ ynormF,
    const short* __restrict__ w1p, const short* __restrict__ w2p,
    const float* __restrict__ b1, const float* __restrict__ b2,
    const float* __restrict__ x, float* __restrict__ out)
{
    __shared__ __align__(16) char smem[65536];
    short* Ash = (short*)smem;               // 32KB, frag-major [ks][mf][lane][8]
    short* Hs0 = (short*)(smem + 32768);     // [64][128] bf16 swizzled, buf 0
    short* Hs1 = (short*)(smem + 49152);     // [64][128] bf16 swizzled, buf 1

    const int tid  = threadIdx.x;
    const int lane = tid & 63;
    const int wid  = tid >> 6;
    const int tile = blockIdx.x;
    const int M0 = tile * 64;
    const int b = M0 >> 16, c = (M0 >> 8) & 255, h0 = M0 & 255;

    const int l15  = lane & 15;
    const int kg   = lane >> 4;   // 0..3

    // stage A tile: linear 32KB copy (already fragment-major in global)
    {
        const uint4* src = reinterpret_cast<const uint4*>(ynormF) + (size_t)tile*2048;
        uint4* dst = reinterpret_cast<uint4*>(Ash);
        for (int i = tid; i < 2048; i += 256) dst[i] = src[i];
    }
    __syncthreads();   // staging loads must complete -> full drain here only

    // acc2 initialized with b2 bias: acc2[mf][nfi][r] -> w = (wid*4+nfi)*16+kg*4+r
    f32x4 acc2[4][4];
    #pragma unroll
    for (int nfi = 0; nfi < 4; ++nfi){
        float4 bv = *reinterpret_cast<const float4*>(b2 + (wid*4 + nfi)*16 + kg*4);
        f32x4 b4 = {bv.x, bv.y, bv.z, bv.w};
        #pragma unroll
        for (int mf = 0; mf < 4; ++mf) acc2[mf][nfi] = b4;
    }

    f32x4 accA[4][2], accB[4][2];
    short8 pw2[4];

    // GEMM1 for o-chunk oc (128 cols), SWAPPED operands:
    // acc1[mf][nfi][r] = P[o = (oc*8+wid*2+nfi)*16 + kg*4 + r][m = mf*16 + l15] + b1[o]
    auto gemm1 = [&](int oc, f32x4 (&acc1)[4][2]){
        #pragma unroll
        for (int nfi = 0; nfi < 2; ++nfi){
            float4 bv = *reinterpret_cast<const float4*>(
                b1 + oc*128 + (wid*2 + nfi)*16 + kg*4);
            f32x4 bi = {bv.x, bv.y, bv.z, bv.w};
            #pragma unroll
            for (int mf = 0; mf < 4; ++mf) acc1[mf][nfi] = bi;
        }
        #pragma unroll
        for (int ks = 0; ks < 8; ++ks){
            short8 afr[4], bfr[2];
            #pragma unroll
            for (int mf = 0; mf < 4; ++mf)
                afr[mf] = *reinterpret_cast<const short8*>(
                    Ash + ((ks*4 + mf)*64 + lane)*8);
            #pragma unroll
            for (int nfi = 0; nfi < 2; ++nfi)
                bfr[nfi] = *reinterpret_cast<const short8*>(
                    w1p + ((size_t)(((oc*8 + wid*2 + nfi)*8 + ks)*64 + lane)) * 8);
            #pragma unroll
            for (int mf = 0; mf < 4; ++mf)
                #pragma unroll
                for (int nfi = 0; nfi < 2; ++nfi)
                    acc1[mf][nfi] = mfma16(bfr[nfi], afr[mf], acc1[mf][nfi]);
        }
    };

    // GELU + pack -> Hb: one b64 store per (nfi, mf): H[m][o..o+3]
    // byte layout identical to gemm2's read: chunk8 ^= (m&7)
    auto gelu_store = [&](f32x4 (&acc1)[4][2], short* Hb){
        #pragma unroll
        for (int nfi = 0; nfi < 2; ++nfi){
            int chunkbase = (wid*2 + nfi)*2 + (kg >> 1);   // o>>3
            int osub = (kg & 1) << 2;                      // o&7 (4-aligned)
            #pragma unroll
            for (int mf = 0; mf < 4; ++mf){
                int m = mf*16 + l15;
                uint2 pv;
                pv.x = pk2(gelu_fast(acc1[mf][nfi][0]), gelu_fast(acc1[mf][nfi][1]));
                pv.y = pk2(gelu_fast(acc1[mf][nfi][2]), gelu_fast(acc1[mf][nfi][3]));
                *reinterpret_cast<uint2*>(
                    Hb + m*128 + ((chunkbase ^ (m & 7)) << 3) + osub) = pv;
            }
        }
    };

    auto prefetch_pw2 = [&](int oc){
        #pragma unroll
        for (int nfi = 0; nfi < 4; ++nfi)
            pw2[nfi] = *reinterpret_cast<const short8*>(
                w2p + ((size_t)(((wid*4 + nfi)*32 + oc*4 + 0)*64 + lane)) * 8);
    };

    // GEMM2 partial (SWAPPED): Out2^T[w][m] += W2-slice @ H-chunk^T
    auto gemm2f = [&](int oc, short* Hb){
        #pragma unroll
        for (int ks = 0; ks < 4; ++ks){
            short8 hfr[4], wfr[4];
            #pragma unroll
            for (int mf = 0; mf < 4; ++mf){
                int row = mf*16 + l15;
                hfr[mf] = *reinterpret_cast<const short8*>(
                    Hb + row*128 + (((ks*4 + kg) ^ (l15 & 7)) << 3));
            }
            if (ks == 0){
                #pragma unroll
                for (int nfi = 0; nfi < 4; ++nfi) wfr[nfi] = pw2[nfi];
            } else {
                #pragma unroll
                for (int nfi = 0; nfi < 4; ++nfi)
                    wfr[nfi] = *reinterpret_cast<const short8*>(
                        w2p + ((size_t)(((wid*4 + nfi)*32 + oc*4 + ks)*64 + lane)) * 8);
            }
            #pragma unroll
            for (int mf = 0; mf < 4; ++mf)
                #pragma unroll
                for (int nfi = 0; nfi < 4; ++nfi)
                    acc2[mf][nfi] = mfma16(wfr[nfi], hfr[mf], acc2[mf][nfi]);
        }
    };

    // prologue: fill the 2-deep pipeline
    gemm1(0, accA);
    gelu_store(accA, Hs0);
    gemm1(1, accB);
    prefetch_pw2(0);
    barrier_lds();

    #pragma unroll
    for (int oc = 0; oc < 8; ++oc){
        short* Hcur = (oc & 1) ? Hs1 : Hs0;
        gemm2f(oc, Hcur);
        if (oc < 7){
            f32x4 (&accR)[4][2] = ((oc + 1) & 1) ? accB : accA;
            gelu_store(accR, (oc & 1) ? Hs0 : Hs1);
        }
        if (oc < 6){
            f32x4 (&accW)[4][2] = ((oc + 2) & 1) ? accB : accA;
            gemm1(oc + 2, accW);
        }
        if (oc < 7){
            prefetch_pw2(oc + 1);
            barrier_lds();   // LDS-only drain: weight loads stay in flight
        }
    }

    // ---- barrier-free epilogue (bias already in acc2):
    // acc2[mf][nfi][r] = Out2^T[w = (wid*4+nfi)*16 + kg*4 + r][m = mf*16 + l15]
    #pragma unroll
    for (int nfi = 0; nfi < 4; ++nfi){
        #pragma unroll
        for (int r = 0; r < 4; ++r){
            int w = (wid*4 + nfi)*16 + kg*4 + r;
            size_t base = ((size_t)b << 24) + ((size_t)w << 16) + (c << 8) + h0 + l15;
            #pragma unroll
            for (int mf = 0; mf < 4; ++mf){
                size_t o = base + mf*16;
                out[o] = acc2[mf][nfi][r] + x[o];
            }
        }
    }
}

// ---------------------------------------------------------------- launch
extern "C" void kernel_launch(void* const* d_in, const int* in_sizes, int n_in,
                              void* d_out, int out_size, void* d_ws, size_t ws_size,
                              hipStream_t stream)
{
    const float* x      = (const float*)d_in[0];
    const float* conv_w = (const float*)d_in[1];
    const float* conv_b = (const float*)d_in[2];
    const float* ln_g   = (const float*)d_in[3];
    const float* ln_b   = (const float*)d_in[4];
    const float* w1     = (const float*)d_in[5];
    const float* b1     = (const float*)d_in[6];
    const float* w2     = (const float*)d_in[7];
    const float* b2     = (const float*)d_in[8];
    float* out = (float*)d_out;

    unsigned short* ynormF = (unsigned short*)d_ws;                         // 67,108,864 B
    unsigned short* w1p    = (unsigned short*)((char*)d_ws + 67108864);     //    524,288 B
    unsigned short* w2p    = (unsigned short*)((char*)d_ws + 67108864 + 524288);

    hipLaunchKernelGGL(prep_weights, dim3(256), dim3(256), 0, stream, w1, w2, w1p, w2p);
    hipLaunchKernelGGL(conv_ln_kernel, dim3(8192), dim3(256), 0, stream,
                       x, conv_w, conv_b, ln_g, ln_b, ynormF);
    hipLaunchKernelGGL(mlp_kernel, dim3(2048), dim3(256), 0, stream,
                       ynormF, (const short*)w1p, (const short*)w2p, b1, b2, x, out);
}

// Round 16
// 234.493 us; speedup vs baseline: 2.7248x; 1.0175x over previous
//
#include <hip/hip_runtime.h>
#include <hip/hip_bf16.h>
#include <math.h>

using short8 = __attribute__((ext_vector_type(8))) short;
using f32x4  = __attribute__((ext_vector_type(4))) float;

static __device__ __forceinline__ f32x4 mfma16(short8 a, short8 b, f32x4 c){
    return __builtin_amdgcn_mfma_f32_16x16x32_bf16(a, b, c, 0, 0, 0);
}

// round-to-nearest-even f32 -> bf16 bits (finite values only)
static __device__ __forceinline__ unsigned short bf16of(float f){
    unsigned int u = __float_as_uint(f);
    unsigned int lsb = (u >> 16) & 1u;
    u += 0x7fffu + lsb;
    return (unsigned short)(u >> 16);
}

// pack two f32 -> two bf16 (round-half-up) via v_perm
static __device__ __forceinline__ unsigned int pk2(float lo, float hi){
    return __builtin_amdgcn_perm(__float_as_uint(hi) + 0x8000u,
                                 __float_as_uint(lo) + 0x8000u, 0x07060302u);
}

// sigmoid-form GELU: x * sigmoid(1.702 x), exp2-folded (5 VALU ops).
static __device__ __forceinline__ float gelu_fast(float x){
    float e = __builtin_amdgcn_exp2f(-2.4554669596f * x);
    return x * __builtin_amdgcn_rcpf(1.0f + e);
}

// ---------------------------------------------------------------- conv + LN + (fused) weight prep
// Grid: 8192 conv blocks + 128 prep blocks, 512 threads each.
// conv: one block = 16 h-rows of one (b,c) plane; 8 waves, 2 rows/thread ->
// 32 waves/CU (wave cap) at 31.7KB LDS. Wave-register LN (wave hs owns rows
// hs*2, hs*2+1 fully). Output written fragment-major for the MLP.
// prep blocks (blk >= 8192): pack w1/w2 into MFMA-fragment-major bf16,
// running concurrently with conv instead of as a serial launch.
#define CH 16          // output h-rows per conv block
#define XR (CH + 6)    // input rows incl. halo
#define XWV 66         // float4 chunks per tile row
#define XW 264         // floats per tile row (tile col = gw + 4)

__global__ __launch_bounds__(512) void conv_ln_prep_kernel(
    const float* __restrict__ x, const float* __restrict__ conv_w,
    const float* __restrict__ conv_b, const float* __restrict__ ln_g,
    const float* __restrict__ ln_b, unsigned short* __restrict__ ynormF,
    const float* __restrict__ w1, const float* __restrict__ w2,
    unsigned short* __restrict__ w1p, unsigned short* __restrict__ w2p)
{
    __shared__ float xt[XR * XW];              // 23232 B
    __shared__ unsigned short ytn[CH * 264];   //  8448 B

    const int tid = threadIdx.x;
    const int blk = blockIdx.x;

    if (blk >= 8192){
        // ---------------- prep path (128 blocks x 512 thr = 65536 tasks)
        int t = (blk - 8192)*512 + tid;
        int lane = t & 63;
        if (t < 32768){
            int g = t;
            int ks  = (g >> 6) & 7;
            int n16 = g >> 9;
            int o = n16*16 + (lane & 15);
            int k = ks*32 + (lane >> 4)*8;
            const float* src = w1 + o*256 + k;
            unsigned short* dst = w1p + (size_t)g*8;
            #pragma unroll
            for (int j = 0; j < 8; ++j) dst[j] = bf16of(src[j]);
        } else {
            int g = t - 32768;
            int ksg = (g >> 6) & 31;
            int n16 = g >> 11;
            int n = n16*16 + (lane & 15);
            int k = ksg*32 + (lane >> 4)*8;
            const float* src = w2 + n*1024 + k;
            unsigned short* dst = w2p + (size_t)g*8;
            #pragma unroll
            for (int j = 0; j < 8; ++j) dst[j] = bf16of(src[j]);
        }
        return;
    }

    // ---------------- conv path
    const int ht = blk & 15;
    const int c  = (blk >> 4) & 255;
    const int b  = blk >> 12;
    const int h0 = ht * CH;

    const float* xplane = x + (((size_t)(b*256 + c)) << 16);

    // stage x tile: 22 rows x 66 aligned float4 chunks
    for (int i = tid; i < XR*XWV; i += 512){
        int ir = i / XWV;
        int cc = i - ir*XWV;
        int gh = h0 - 3 + ir;
        float4 v = make_float4(0.f, 0.f, 0.f, 0.f);
        if ((unsigned)gh < 256u && (unsigned)(cc - 1) < 64u)
            v = *reinterpret_cast<const float4*>(xplane + gh*256 + (cc - 1)*4);
        *reinterpret_cast<float4*>(&xt[ir*XW + cc*4]) = v;
    }

    float cwr[49];
    #pragma unroll
    for (int i = 0; i < 49; ++i) cwr[i] = conv_w[c*49 + i];
    const float cb = conv_b[c];

    __syncthreads();

    // thread (wq, hs): out cols 4wq..4wq+3, out rows hs*2, hs*2+1 (local)
    const int wq = tid & 63;
    const int hs = tid >> 6;   // 0..7
    float acc[2][4] = {};      // [ro][cc]

    #pragma unroll
    for (int d = 0; d < 8; ++d){
        int ir = hs*2 + d;
        float4 ra = *reinterpret_cast<const float4*>(&xt[ir*XW + wq*4]);
        float4 rb = *reinterpret_cast<const float4*>(&xt[ir*XW + wq*4 + 4]);
        float4 rc = *reinterpret_cast<const float4*>(&xt[ir*XW + wq*4 + 8]);
        float rr[12] = {ra.x, ra.y, ra.z, ra.w, rb.x, rb.y, rb.z, rb.w,
                        rc.x, rc.y, rc.z, rc.w};
        #pragma unroll
        for (int ro = 0; ro < 2; ++ro){
            int dh = d - ro;
            if (dh >= 0 && dh <= 6){
                #pragma unroll
                for (int dw = 0; dw < 7; ++dw){
                    float wv = cwr[dh*7 + dw];
                    #pragma unroll
                    for (int cc = 0; cc < 4; ++cc)
                        acc[ro][cc] = fmaf(rr[cc + dw + 1], wv, acc[ro][cc]);
                }
            }
        }
    }

    // add conv bias now (LN stats need it)
    #pragma unroll
    for (int ro = 0; ro < 2; ++ro)
        #pragma unroll
        for (int cc = 0; cc < 4; ++cc)
            acc[ro][cc] += cb;

    // LN gamma/beta for this thread's 4 cols
    const float4 lgv = *reinterpret_cast<const float4*>(ln_g + wq*4);
    const float4 lbv = *reinterpret_cast<const float4*>(ln_b + wq*4);
    const float lg[4] = {lgv.x, lgv.y, lgv.z, lgv.w};
    const float lb[4] = {lbv.x, lbv.y, lbv.z, lbv.w};

    // per-row LN via 64-lane shuffle reduce; write bf16 to ytn (b64 stores)
    #pragma unroll
    for (int ro = 0; ro < 2; ++ro){
        float s  = acc[ro][0] + acc[ro][1] + acc[ro][2] + acc[ro][3];
        float ss = acc[ro][0]*acc[ro][0] + acc[ro][1]*acc[ro][1]
                 + acc[ro][2]*acc[ro][2] + acc[ro][3]*acc[ro][3];
        #pragma unroll
        for (int off = 32; off > 0; off >>= 1){
            s  += __shfl_xor(s, off);
            ss += __shfl_xor(ss, off);
        }
        float mu  = s * (1.f/256.f);
        float var = ss * (1.f/256.f) - mu*mu;
        float rs  = rsqrtf(var + 1e-5f);
        float o0 = (acc[ro][0] - mu)*rs*lg[0] + lb[0];
        float o1 = (acc[ro][1] - mu)*rs*lg[1] + lb[1];
        float o2 = (acc[ro][2] - mu)*rs*lg[2] + lb[2];
        float o3 = (acc[ro][3] - mu)*rs*lg[3] + lb[3];
        uint2 pv;
        pv.x = (unsigned int)bf16of(o0) | ((unsigned int)bf16of(o1) << 16);
        pv.y = (unsigned int)bf16of(o2) | ((unsigned int)bf16of(o3) << 16);
        *reinterpret_cast<uint2*>(&ytn[(hs*2 + ro)*264 + wq*4]) = pv;
    }

    __syncthreads();

    // fragment-major global write: frag (ks, mf, lane=kg*16+l15, j) =
    // Y[tile*64 + mf*16 + l15][ks*32 + kg*8 + j]; this block owns mf fixed.
    // 8 waves -> wave wv handles ks = wv (one uint4 per thread).
    {
        const int l   = tid & 63;
        const int ks  = tid >> 6;
        const int l15w = l & 15, kgw = l >> 4;
        const int tile = (((b*256 + c)*256 + h0) >> 6);
        const int mf = (h0 >> 4) & 3;
        uint4* dst = reinterpret_cast<uint4*>(ynormF) + (size_t)tile*2048;
        uint4 v = *reinterpret_cast<const uint4*>(ytn + l15w*264 + ks*32 + kgw*8);
        dst[(ks*4 + mf)*64 + l] = v;
    }
}

// ---------------------------------------------------------------- fused MLP + transposed-out residual
// (R11 structure — best measured 162 us.)
// 4 waves, M-tile 64, waves split N. o-chunks of 128, Hs double-buffered,
// acc1 double-buffered, rotated regions { gemm2(oc); gelu(oc+1); gemm1(oc+2) }.
// A staged in LDS frag-major (conflict-free lane-contiguous ds_read_b128).
// GEMM1 SWAPPED: mfma(W1,Y) -> P^T[o][m], b64 H-stores. GEMM2 SWAPPED:
// mfma(W2,H) -> Out2^T[w][m] -> barrier-free coalesced epilogue + residual.
// Lessons: R9 A-in-registers spills; R13 launch_bounds(,4) forces spill;
// R14 occupancy is register-walled (unified VGPR+AGPR ~256/thread), A-from-L1
// regresses; R15 LDS-only barriers neutral (waves not vmcnt-drain-bound).
__global__ __launch_bounds__(256, 2) void mlp_kernel(
    const unsigned short* __restrict__ ynormF,
    const short* __restrict__ w1p, const short* __restrict__ w2p,
    const float* __restrict__ b1, const float* __restrict__ b2,
    const float* __restrict__ x, float* __restrict__ out)
{
    __shared__ __align__(16) char smem[65536];
    short* Ash = (short*)smem;               // 32KB, frag-major [ks][mf][lane][8]
    short* Hs0 = (short*)(smem + 32768);     // [64][128] bf16 swizzled, buf 0
    short* Hs1 = (short*)(smem + 49152);     // [64][128] bf16 swizzled, buf 1

    const int tid  = threadIdx.x;
    const int lane = tid & 63;
    const int wid  = tid >> 6;
    const int tile = blockIdx.x;
    const int M0 = tile * 64;
    const int b = M0 >> 16, c = (M0 >> 8) & 255, h0 = M0 & 255;

    const int l15  = lane & 15;
    const int kg   = lane >> 4;   // 0..3

    // stage A tile: linear 32KB copy (already fragment-major in global)
    {
        const uint4* src = reinterpret_cast<const uint4*>(ynormF) + (size_t)tile*2048;
        uint4* dst = reinterpret_cast<uint4*>(Ash);
        for (int i = tid; i < 2048; i += 256) dst[i] = src[i];
    }
    __syncthreads();

    // acc2 initialized with b2 bias: acc2[mf][nfi][r] -> w = (wid*4+nfi)*16+kg*4+r
    f32x4 acc2[4][4];
    #pragma unroll
    for (int nfi = 0; nfi < 4; ++nfi){
        float4 bv = *reinterpret_cast<const float4*>(b2 + (wid*4 + nfi)*16 + kg*4);
        f32x4 b4 = {bv.x, bv.y, bv.z, bv.w};
        #pragma unroll
        for (int mf = 0; mf < 4; ++mf) acc2[mf][nfi] = b4;
    }

    f32x4 accA[4][2], accB[4][2];
    short8 pw2[4];

    // GEMM1 for o-chunk oc (128 cols), SWAPPED operands:
    // acc1[mf][nfi][r] = P[o = (oc*8+wid*2+nfi)*16 + kg*4 + r][m = mf*16 + l15] + b1[o]
    auto gemm1 = [&](int oc, f32x4 (&acc1)[4][2]){
        #pragma unroll
        for (int nfi = 0; nfi < 2; ++nfi){
            float4 bv = *reinterpret_cast<const float4*>(
                b1 + oc*128 + (wid*2 + nfi)*16 + kg*4);
            f32x4 bi = {bv.x, bv.y, bv.z, bv.w};
            #pragma unroll
            for (int mf = 0; mf < 4; ++mf) acc1[mf][nfi] = bi;
        }
        #pragma unroll
        for (int ks = 0; ks < 8; ++ks){
            short8 afr[4], bfr[2];
            #pragma unroll
            for (int mf = 0; mf < 4; ++mf)
                afr[mf] = *reinterpret_cast<const short8*>(
                    Ash + ((ks*4 + mf)*64 + lane)*8);
            #pragma unroll
            for (int nfi = 0; nfi < 2; ++nfi)
                bfr[nfi] = *reinterpret_cast<const short8*>(
                    w1p + ((size_t)(((oc*8 + wid*2 + nfi)*8 + ks)*64 + lane)) * 8);
            #pragma unroll
            for (int mf = 0; mf < 4; ++mf)
                #pragma unroll
                for (int nfi = 0; nfi < 2; ++nfi)
                    acc1[mf][nfi] = mfma16(bfr[nfi], afr[mf], acc1[mf][nfi]);
        }
    };

    // GELU + pack -> Hb: one b64 store per (nfi, mf): H[m][o..o+3]
    // byte layout identical to gemm2's read: chunk8 ^= (m&7)
    auto gelu_store = [&](f32x4 (&acc1)[4][2], short* Hb){
        #pragma unroll
        for (int nfi = 0; nfi < 2; ++nfi){
            int chunkbase = (wid*2 + nfi)*2 + (kg >> 1);   // o>>3
            int osub = (kg & 1) << 2;                      // o&7 (4-aligned)
            #pragma unroll
            for (int mf = 0; mf < 4; ++mf){
                int m = mf*16 + l15;
                uint2 pv;
                pv.x = pk2(gelu_fast(acc1[mf][nfi][0]), gelu_fast(acc1[mf][nfi][1]));
                pv.y = pk2(gelu_fast(acc1[mf][nfi][2]), gelu_fast(acc1[mf][nfi][3]));
                *reinterpret_cast<uint2*>(
                    Hb + m*128 + ((chunkbase ^ (m & 7)) << 3) + osub) = pv;
            }
        }
    };

    auto prefetch_pw2 = [&](int oc){
        #pragma unroll
        for (int nfi = 0; nfi < 4; ++nfi)
            pw2[nfi] = *reinterpret_cast<const short8*>(
                w2p + ((size_t)(((wid*4 + nfi)*32 + oc*4 + 0)*64 + lane)) * 8);
    };

    // GEMM2 partial (SWAPPED): Out2^T[w][m] += W2-slice @ H-chunk^T
    auto gemm2f = [&](int oc, short* Hb){
        #pragma unroll
        for (int ks = 0; ks < 4; ++ks){
            short8 hfr[4], wfr[4];
            #pragma unroll
            for (int mf = 0; mf < 4; ++mf){
                int row = mf*16 + l15;
                hfr[mf] = *reinterpret_cast<const short8*>(
                    Hb + row*128 + (((ks*4 + kg) ^ (l15 & 7)) << 3));
            }
            if (ks == 0){
                #pragma unroll
                for (int nfi = 0; nfi < 4; ++nfi) wfr[nfi] = pw2[nfi];
            } else {
                #pragma unroll
                for (int nfi = 0; nfi < 4; ++nfi)
                    wfr[nfi] = *reinterpret_cast<const short8*>(
                        w2p + ((size_t)(((wid*4 + nfi)*32 + oc*4 + ks)*64 + lane)) * 8);
            }
            #pragma unroll
            for (int mf = 0; mf < 4; ++mf)
                #pragma unroll
                for (int nfi = 0; nfi < 4; ++nfi)
                    acc2[mf][nfi] = mfma16(wfr[nfi], hfr[mf], acc2[mf][nfi]);
        }
    };

    // prologue: fill the 2-deep pipeline
    gemm1(0, accA);
    gelu_store(accA, Hs0);
    gemm1(1, accB);
    prefetch_pw2(0);
    __syncthreads();

    #pragma unroll
    for (int oc = 0; oc < 8; ++oc){
        short* Hcur = (oc & 1) ? Hs1 : Hs0;
        gemm2f(oc, Hcur);
        if (oc < 7){
            f32x4 (&accR)[4][2] = ((oc + 1) & 1) ? accB : accA;
            gelu_store(accR, (oc & 1) ? Hs0 : Hs1);
        }
        if (oc < 6){
            f32x4 (&accW)[4][2] = ((oc + 2) & 1) ? accB : accA;
            gemm1(oc + 2, accW);
        }
        if (oc < 7){
            prefetch_pw2(oc + 1);
            __syncthreads();
        }
    }

    // ---- barrier-free epilogue (bias already in acc2):
    // acc2[mf][nfi][r] = Out2^T[w = (wid*4+nfi)*16 + kg*4 + r][m = mf*16 + l15]
    #pragma unroll
    for (int nfi = 0; nfi < 4; ++nfi){
        #pragma unroll
        for (int r = 0; r < 4; ++r){
            int w = (wid*4 + nfi)*16 + kg*4 + r;
            size_t base = ((size_t)b << 24) + ((size_t)w << 16) + (c << 8) + h0 + l15;
            #pragma unroll
            for (int mf = 0; mf < 4; ++mf){
                size_t o = base + mf*16;
                out[o] = acc2[mf][nfi][r] + x[o];
            }
        }
    }
}

// ---------------------------------------------------------------- launch
extern "C" void kernel_launch(void* const* d_in, const int* in_sizes, int n_in,
                              void* d_out, int out_size, void* d_ws, size_t ws_size,
                              hipStream_t stream)
{
    const float* x      = (const float*)d_in[0];
    const float* conv_w = (const float*)d_in[1];
    const float* conv_b = (const float*)d_in[2];
    const float* ln_g   = (const float*)d_in[3];
    const float* ln_b   = (const float*)d_in[4];
    const float* w1     = (const float*)d_in[5];
    const float* b1     = (const float*)d_in[6];
    const float* w2     = (const float*)d_in[7];
    const float* b2     = (const float*)d_in[8];
    float* out = (float*)d_out;

    unsigned short* ynormF = (unsigned short*)d_ws;                         // 67,108,864 B
    unsigned short* w1p    = (unsigned short*)((char*)d_ws + 67108864);     //    524,288 B
    unsigned short* w2p    = (unsigned short*)((char*)d_ws + 67108864 + 524288);

    hipLaunchKernelGGL(conv_ln_prep_kernel, dim3(8320), dim3(512), 0, stream,
                       x, conv_w, conv_b, ln_g, ln_b, ynormF, w1, w2, w1p, w2p);
    hipLaunchKernelGGL(mlp_kernel, dim3(2048), dim3(256), 0, stream,
                       ynormF, (const short*)w1p, (const short*)w2p, b1, b2, x, out);
}